// Round 1
// baseline (270.831 us; speedup 1.0000x reference)
//
#include <hip/hip_runtime.h>
#include <hip/hip_fp16.h>

// CfC cell: out = ff1*(1-t)+t*ff2 with
//   h   = 1.7159*tanh(0.666*(concat(input,hx) @ Wb^T + bb))   [B,1024]
//   ff1 = tanh(h@W1^T+b1), ff2 = tanh(h@W2^T+b2)
//   t   = sigmoid((h@Wa^T+ba)*ts + (h@Wt^T+bt))               [B,512]
// Strategy: fp16 MFMA (16x16x32_f16), fp32 accum. Two tiled GEMM kernels
// (m97 structure: global_load_lds width-16 staging, 2-barrier K loop).

typedef _Float16 f16;
typedef _Float16 f16x8 __attribute__((ext_vector_type(8)));
typedef _Float16 f16x4 __attribute__((ext_vector_type(4)));
typedef float f32x4 __attribute__((ext_vector_type(4)));

static constexpr int B_ = 16384, IN_ = 256, HID_ = 512, UNITS_ = 1024, CAT_ = 768;

__device__ __forceinline__ void gload_lds16(const void* g, void* l) {
  __builtin_amdgcn_global_load_lds(
      (const __attribute__((address_space(1))) void*)g,
      (__attribute__((address_space(3))) void*)l, 16, 0, 0);
}

// ---- conversion kernels -------------------------------------------------

// x = concat(input, hx) cast to f16, [B][768]
__global__ void build_x_kernel(const float* __restrict__ inp,
                               const float* __restrict__ hx,
                               f16* __restrict__ x) {
  const int per_row = CAT_ / 4;  // 192 float4-groups per row
  int gid = blockIdx.x * blockDim.x + threadIdx.x;
  if (gid >= B_ * per_row) return;
  int b = gid / per_row, j = gid - b * per_row;
  float4 v;
  if (j < IN_ / 4) v = ((const float4*)(inp + (size_t)b * IN_))[j];
  else             v = ((const float4*)(hx  + (size_t)b * HID_))[j - IN_ / 4];
  f16x4 o = {(f16)v.x, (f16)v.y, (f16)v.z, (f16)v.w};
  *((f16x4*)(x + (size_t)b * CAT_ + j * 4)) = o;
}

__global__ void cvt_kernel(const float* __restrict__ s, f16* __restrict__ d, int n4) {
  int i = blockIdx.x * blockDim.x + threadIdx.x;
  if (i >= n4) return;
  float4 v = ((const float4*)s)[i];
  f16x4 o = {(f16)v.x, (f16)v.y, (f16)v.z, (f16)v.w};
  ((f16x4*)d)[i] = o;
}

// ---- GEMM1: h = lecun_tanh(X @ Wb^T + bb) ------------------------------
// X [B][768] f16, Wb [1024][768] f16 (row-major [N][K] == B^T input)
// tile 128x128, BK=32, 4 waves (2x2), wave tile 64x64.

__global__ __launch_bounds__(256) void gemm1_kernel(
    const f16* __restrict__ X, const f16* __restrict__ Wb,
    const float* __restrict__ bb, f16* __restrict__ H) {
  constexpr int BM = 128, BN = 128, BK = 32, K = CAT_, N = UNITS_;
  __shared__ f16 As[BM * BK];
  __shared__ f16 Bs[BN * BK];
  const int t = threadIdx.x;
  const int lane = t & 63, wid = t >> 6;
  const int wr = wid >> 1, wc = wid & 1;
  const int bc = blockIdx.x & 7;   // N/BN = 8
  const int br = blockIdx.x >> 3;
  const size_t arow0 = (size_t)br * BM;
  const size_t brow0 = (size_t)bc * BN;

  f32x4 acc[4][4] = {};

  const int srow = t >> 2;          // 0..63 (staging row within 64-row half)
  const int schunk = (t & 3) * 8;   // f16 offset of 16B chunk
  const f16* aptr0 = X + (arow0 + srow) * K + schunk;
  const f16* aptr1 = X + (arow0 + 64 + srow) * K + schunk;
  const f16* bptr0 = Wb + (brow0 + srow) * K + schunk;
  const f16* bptr1 = Wb + (brow0 + 64 + srow) * K + schunk;
  f16* lA0 = As + t * 8;            // == (srow*BK + schunk), linear in t
  f16* lA1 = As + 64 * BK + t * 8;
  f16* lB0 = Bs + t * 8;
  f16* lB1 = Bs + 64 * BK + t * 8;

  const int fr = lane & 15;         // fragment row/col within 16
  const int koff = (lane >> 4) * 8; // k-offset of this lane's 8 elements

  for (int k0 = 0; k0 < K; k0 += BK) {
    gload_lds16(aptr0 + k0, lA0);
    gload_lds16(aptr1 + k0, lA1);
    gload_lds16(bptr0 + k0, lB0);
    gload_lds16(bptr1 + k0, lB1);
    __syncthreads();
    f16x8 af[4], bf[4];
#pragma unroll
    for (int m = 0; m < 4; ++m)
      af[m] = *((const f16x8*)(As + (wr * 64 + m * 16 + fr) * BK + koff));
#pragma unroll
    for (int n = 0; n < 4; ++n)
      bf[n] = *((const f16x8*)(Bs + (wc * 64 + n * 16 + fr) * BK + koff));
#pragma unroll
    for (int m = 0; m < 4; ++m)
#pragma unroll
      for (int n = 0; n < 4; ++n)
        acc[m][n] = __builtin_amdgcn_mfma_f32_16x16x32_f16(af[m], bf[n], acc[m][n], 0, 0, 0);
    __syncthreads();
  }

#pragma unroll
  for (int m = 0; m < 4; ++m) {
#pragma unroll
    for (int n = 0; n < 4; ++n) {
      const int colg = (int)brow0 + wc * 64 + n * 16 + (lane & 15);
      const float bias = bb[colg];
#pragma unroll
      for (int i = 0; i < 4; ++i) {
        const int rowg = (int)arow0 + wr * 64 + m * 16 + (lane >> 4) * 4 + i;
        float v = acc[m][n][i] + bias;
        v = 1.7159f * tanhf(0.666f * v);
        H[(size_t)rowg * N + colg] = (f16)v;
      }
    }
  }
}

// ---- GEMM2: four heads fused --------------------------------------------
// H [B][1024] f16, W [4][512][1024] f16 (heads: ff1, ff2, t_a, t_b)
// tile 128x64 (per head), BK=32, 4 waves (2x2), wave tile 64x32.

__global__ __launch_bounds__(256) void gemm2_kernel(
    const f16* __restrict__ H, const f16* __restrict__ W,
    const float* __restrict__ b1, const float* __restrict__ b2,
    const float* __restrict__ ba, const float* __restrict__ bt,
    const float* __restrict__ ts, float* __restrict__ out) {
  constexpr int BM = 128, BN = 64, BK = 32, K = UNITS_, N = HID_;
  __shared__ f16 As[BM * BK];        // 8 KB
  __shared__ f16 Bs[4][BN * BK];     // 16 KB
  const int t = threadIdx.x;
  const int lane = t & 63, wid = t >> 6;
  const int wr = wid >> 1, wc = wid & 1;
  const int bc = blockIdx.x & 7;     // N/BN = 8
  const int br = blockIdx.x >> 3;
  const size_t arow0 = (size_t)br * BM;
  const size_t brow0 = (size_t)bc * BN;

  f32x4 acc[4][4][2] = {};  // [head][m][n]

  const int srow = t >> 2;
  const int schunk = (t & 3) * 8;
  const f16* aptr0 = H + (arow0 + srow) * K + schunk;
  const f16* aptr1 = H + (arow0 + 64 + srow) * K + schunk;
  const f16* bptr[4];
#pragma unroll
  for (int h = 0; h < 4; ++h)
    bptr[h] = W + ((size_t)h * N + brow0 + srow) * K + schunk;
  f16* lA0 = As + t * 8;
  f16* lA1 = As + 64 * BK + t * 8;

  const int fr = lane & 15;
  const int koff = (lane >> 4) * 8;

  for (int k0 = 0; k0 < K; k0 += BK) {
    gload_lds16(aptr0 + k0, lA0);
    gload_lds16(aptr1 + k0, lA1);
#pragma unroll
    for (int h = 0; h < 4; ++h)
      gload_lds16(bptr[h] + k0, &Bs[h][t * 8]);
    __syncthreads();
    f16x8 af[4];
#pragma unroll
    for (int m = 0; m < 4; ++m)
      af[m] = *((const f16x8*)(As + (wr * 64 + m * 16 + fr) * BK + koff));
#pragma unroll
    for (int h = 0; h < 4; ++h) {
      f16x8 bf[2];
#pragma unroll
      for (int n = 0; n < 2; ++n)
        bf[n] = *((const f16x8*)(&Bs[h][0] + (wc * 32 + n * 16 + fr) * BK + koff));
#pragma unroll
      for (int m = 0; m < 4; ++m)
#pragma unroll
        for (int n = 0; n < 2; ++n)
          acc[h][m][n] = __builtin_amdgcn_mfma_f32_16x16x32_f16(af[m], bf[n], acc[h][m][n], 0, 0, 0);
    }
    __syncthreads();
  }

#pragma unroll
  for (int m = 0; m < 4; ++m) {
#pragma unroll
    for (int n = 0; n < 2; ++n) {
      const int colg = (int)brow0 + wc * 32 + n * 16 + (lane & 15);
      const float B1 = b1[colg], B2 = b2[colg], BA = ba[colg], BT = bt[colg];
#pragma unroll
      for (int i = 0; i < 4; ++i) {
        const int rowg = (int)arow0 + wr * 64 + m * 16 + (lane >> 4) * 4 + i;
        const float ff1 = tanhf(acc[0][m][n][i] + B1);
        const float ff2 = tanhf(acc[1][m][n][i] + B2);
        const float ta = acc[2][m][n][i] + BA;
        const float tb = acc[3][m][n][i] + BT;
        const float z = ta * ts[rowg] + tb;
        const float ti = 1.0f / (1.0f + __expf(-z));
        out[(size_t)rowg * N + colg] = ff1 + ti * (ff2 - ff1);
      }
    }
  }
}

// ---- launch -------------------------------------------------------------

extern "C" void kernel_launch(void* const* d_in, const int* in_sizes, int n_in,
                              void* d_out, int out_size, void* d_ws, size_t ws_size,
                              hipStream_t stream) {
  const float* input = (const float*)d_in[0];
  const float* hx    = (const float*)d_in[1];
  const float* ts    = (const float*)d_in[2];
  const float* Wb    = (const float*)d_in[3];
  const float* bb    = (const float*)d_in[4];
  const float* W1    = (const float*)d_in[5];
  const float* b1    = (const float*)d_in[6];
  const float* W2    = (const float*)d_in[7];
  const float* b2    = (const float*)d_in[8];
  const float* Wa    = (const float*)d_in[9];
  const float* ba    = (const float*)d_in[10];
  const float* Wt    = (const float*)d_in[11];
  const float* bt    = (const float*)d_in[12];
  float* out = (float*)d_out;

  char* ws = (char*)d_ws;
  f16* x_f16  = (f16*)ws;  ws += (size_t)B_ * CAT_ * 2;        // 25.2 MB
  f16* h_f16  = (f16*)ws;  ws += (size_t)B_ * UNITS_ * 2;      // 33.6 MB
  f16* Wb_f16 = (f16*)ws;  ws += (size_t)UNITS_ * CAT_ * 2;    // 1.6 MB
  f16* Wh_f16 = (f16*)ws;  ws += (size_t)4 * HID_ * UNITS_ * 2;// 4.2 MB

  build_x_kernel<<<(B_ * (CAT_ / 4) + 255) / 256, 256, 0, stream>>>(input, hx, x_f16);
  cvt_kernel<<<(UNITS_ * CAT_ / 4 + 255) / 256, 256, 0, stream>>>(Wb, Wb_f16, UNITS_ * CAT_ / 4);
  cvt_kernel<<<(HID_ * UNITS_ / 4 + 255) / 256, 256, 0, stream>>>(W1, Wh_f16 + (size_t)0 * HID_ * UNITS_, HID_ * UNITS_ / 4);
  cvt_kernel<<<(HID_ * UNITS_ / 4 + 255) / 256, 256, 0, stream>>>(W2, Wh_f16 + (size_t)1 * HID_ * UNITS_, HID_ * UNITS_ / 4);
  cvt_kernel<<<(HID_ * UNITS_ / 4 + 255) / 256, 256, 0, stream>>>(Wa, Wh_f16 + (size_t)2 * HID_ * UNITS_, HID_ * UNITS_ / 4);
  cvt_kernel<<<(HID_ * UNITS_ / 4 + 255) / 256, 256, 0, stream>>>(Wt, Wh_f16 + (size_t)3 * HID_ * UNITS_, HID_ * UNITS_ / 4);

  gemm1_kernel<<<dim3(128 * 8), 256, 0, stream>>>(x_f16, Wb_f16, bb, h_f16);
  gemm2_kernel<<<dim3(128 * 8), 256, 0, stream>>>(h_f16, Wh_f16, b1, b2, ba, bt, ts, out);
}

// Round 2
// 171.936 us; speedup vs baseline: 1.5752x; 1.5752x over previous
//
#include <hip/hip_runtime.h>

// CfC cell, fp16-MFMA implementation.
//   h   = 1.7159*tanh(0.666*(concat(input,hx) @ Wb^T + bb))   [B,1024]
//   ff1 = tanh(h@W1^T+b1), ff2 = tanh(h@W2^T+b2)
//   t   = sigmoid((h@Wa^T+ba)*ts + (h@Wt^T+bt))
//   out = ff1 + t*(ff2-ff1)                                   [B,512]
// Round 2: 2-phase double-buffer (gemm1), 3-buffer counted-vmcnt pipeline
// (gemm2, T3+T4), XCD swizzle (T1), fused weight casts.

typedef _Float16 f16;
typedef _Float16 f16x8 __attribute__((ext_vector_type(8)));
typedef _Float16 f16x4 __attribute__((ext_vector_type(4)));
typedef float f32x4 __attribute__((ext_vector_type(4)));

static constexpr int B_ = 16384, IN_ = 256, HID_ = 512, UNITS_ = 1024, CAT_ = 768;

__device__ __forceinline__ void gload_lds16(const void* g, void* l) {
  __builtin_amdgcn_global_load_lds(
      (const __attribute__((address_space(1))) void*)g,
      (__attribute__((address_space(3))) void*)l, 16, 0, 0);
}

// ---- conversion kernels -------------------------------------------------

__global__ void build_x_kernel(const float* __restrict__ inp,
                               const float* __restrict__ hx,
                               f16* __restrict__ x) {
  const int per_row = CAT_ / 4;  // 192 float4-groups per row
  int gid = blockIdx.x * blockDim.x + threadIdx.x;
  if (gid >= B_ * per_row) return;
  int b = gid / per_row, j = gid - b * per_row;
  float4 v;
  if (j < IN_ / 4) v = ((const float4*)(inp + (size_t)b * IN_))[j];
  else             v = ((const float4*)(hx  + (size_t)b * HID_))[j - IN_ / 4];
  f16x4 o = {(f16)v.x, (f16)v.y, (f16)v.z, (f16)v.w};
  *((f16x4*)(x + (size_t)b * CAT_ + j * 4)) = o;
}

// all 5 weight matrices cast in one launch; seg = blockIdx.y
__global__ void cvt_all_kernel(const float* __restrict__ Wb,
                               const float* __restrict__ W1,
                               const float* __restrict__ W2,
                               const float* __restrict__ Wa,
                               const float* __restrict__ Wt,
                               f16* __restrict__ dWb, f16* __restrict__ dWh) {
  const int seg = blockIdx.y;
  const int i = blockIdx.x * blockDim.x + threadIdx.x;
  const float* s;
  f16* d;
  int n4;
  if (seg == 0) {
    s = Wb; d = dWb; n4 = UNITS_ * CAT_ / 4;
  } else {
    const float* srcs[4] = {W1, W2, Wa, Wt};
    s = srcs[seg - 1];
    d = dWh + (size_t)(seg - 1) * HID_ * UNITS_;
    n4 = HID_ * UNITS_ / 4;
  }
  if (i >= n4) return;
  float4 v = ((const float4*)s)[i];
  f16x4 o = {(f16)v.x, (f16)v.y, (f16)v.z, (f16)v.w};
  ((f16x4*)d)[i] = o;
}

// ---- GEMM1: h = lecun_tanh(X @ Wb^T + bb) ------------------------------
// 128x128 tile, BK=32, 4 waves (2x2). 2-phase double-buffered staging.

__global__ __launch_bounds__(256) void gemm1_kernel(
    const f16* __restrict__ X, const f16* __restrict__ Wb,
    const float* __restrict__ bb, f16* __restrict__ H) {
  constexpr int BM = 128, BN = 128, BK = 32, K = CAT_, N = UNITS_;
  constexpr int NT = K / BK;  // 24
  __shared__ f16 As[2][BM * BK];
  __shared__ f16 Bs[2][BN * BK];
  const int t = threadIdx.x;
  const int lane = t & 63, wid = t >> 6;
  const int wr = wid >> 1, wc = wid & 1;
  // XCD swizzle: 1024 blocks, 8 XCDs, 128 contiguous tiles per XCD
  const int wg = (blockIdx.x & 7) * 128 + (blockIdx.x >> 3);
  const int bc = wg & 7;    // N/BN = 8
  const int br = wg >> 3;
  const size_t arow0 = (size_t)br * BM;
  const size_t brow0 = (size_t)bc * BN;

  f32x4 acc[4][4] = {};

  const int srow = t >> 2;
  const int schunk = (t & 3) * 8;
  const f16* aptr0 = X + (arow0 + srow) * K + schunk;
  const f16* aptr1 = X + (arow0 + 64 + srow) * K + schunk;
  const f16* bptr0 = Wb + (brow0 + srow) * K + schunk;
  const f16* bptr1 = Wb + (brow0 + 64 + srow) * K + schunk;
  const int l8 = t * 8;
  const int fr = lane & 15;
  const int koff = (lane >> 4) * 8;

#define STAGE1(buf, k0)                               \
  do {                                                \
    gload_lds16(aptr0 + (k0), &As[buf][l8]);          \
    gload_lds16(aptr1 + (k0), &As[buf][64 * BK + l8]);\
    gload_lds16(bptr0 + (k0), &Bs[buf][l8]);          \
    gload_lds16(bptr1 + (k0), &Bs[buf][64 * BK + l8]);\
  } while (0)

  STAGE1(0, 0);
  __syncthreads();  // tile 0 landed (vmcnt(0) drain)

  for (int tt = 0; tt < NT; ++tt) {
    const int cur = tt & 1;
    if (tt + 1 < NT) STAGE1(cur ^ 1, (tt + 1) * BK);  // overlap with compute
    f16x8 af[4], bf[4];
#pragma unroll
    for (int m = 0; m < 4; ++m)
      af[m] = *((const f16x8*)(&As[cur][(wr * 64 + m * 16 + fr) * BK + koff]));
#pragma unroll
    for (int n = 0; n < 4; ++n)
      bf[n] = *((const f16x8*)(&Bs[cur][(wc * 64 + n * 16 + fr) * BK + koff]));
#pragma unroll
    for (int m = 0; m < 4; ++m)
#pragma unroll
      for (int n = 0; n < 4; ++n)
        acc[m][n] = __builtin_amdgcn_mfma_f32_16x16x32_f16(af[m], bf[n], acc[m][n], 0, 0, 0);
    __syncthreads();  // drains vmcnt(0): tile tt+1 landed, reads of buf cur done
  }
#undef STAGE1

#pragma unroll
  for (int m = 0; m < 4; ++m) {
#pragma unroll
    for (int n = 0; n < 4; ++n) {
      const int colg = (int)brow0 + wc * 64 + n * 16 + (lane & 15);
      const float bias = bb[colg];
#pragma unroll
      for (int i = 0; i < 4; ++i) {
        const int rowg = (int)arow0 + wr * 64 + m * 16 + (lane >> 4) * 4 + i;
        float v = acc[m][n][i] + bias;
        v = 1.7159f * tanhf(0.666f * v);
        H[(size_t)rowg * N + colg] = (f16)v;
      }
    }
  }
}

// ---- GEMM2: four heads fused, 3-buffer counted-vmcnt pipeline -----------
// 128x64-per-head tile, BK=32, 4 waves (2x2). Prefetch distance 2.

__global__ __launch_bounds__(256) void gemm2_kernel(
    const f16* __restrict__ H, const f16* __restrict__ W,
    const float* __restrict__ b1, const float* __restrict__ b2,
    const float* __restrict__ ba, const float* __restrict__ bt,
    const float* __restrict__ ts, float* __restrict__ out) {
  constexpr int BM = 128, BN = 64, BK = 32, K = UNITS_, N = HID_;
  constexpr int NT = K / BK;  // 32
  __shared__ f16 As[3][BM * BK];      // 24 KB
  __shared__ f16 Bs[3][4][BN * BK];   // 48 KB
  const int t = threadIdx.x;
  const int lane = t & 63, wid = t >> 6;
  const int wr = wid >> 1, wc = wid & 1;
  const int wg = (blockIdx.x & 7) * 128 + (blockIdx.x >> 3);
  const int bc = wg & 7;    // N/BN = 8
  const int br = wg >> 3;
  const size_t arow0 = (size_t)br * BM;
  const size_t brow0 = (size_t)bc * BN;

  f32x4 acc[4][4][2] = {};  // [head][m][n]

  const int srow = t >> 2;
  const int schunk = (t & 3) * 8;
  const f16* aptr0 = H + (arow0 + srow) * K + schunk;
  const f16* aptr1 = H + (arow0 + 64 + srow) * K + schunk;
  const f16* bptrs[4];
#pragma unroll
  for (int h = 0; h < 4; ++h)
    bptrs[h] = W + ((size_t)h * N + brow0 + srow) * K + schunk;
  const int l8 = t * 8;
  const int fr = lane & 15;
  const int koff = (lane >> 4) * 8;

  auto stage = [&](int buf, int k0) {
    gload_lds16(aptr0 + k0, &As[buf][l8]);
    gload_lds16(aptr1 + k0, &As[buf][64 * BK + l8]);
#pragma unroll
    for (int h = 0; h < 4; ++h)
      gload_lds16(bptrs[h] + k0, &Bs[buf][h][l8]);
  };

  // prologue: tiles 0 and 1 in flight; wait tile 0 (6 loads/tile -> vmcnt(6))
  stage(0, 0);
  stage(1, BK);
  asm volatile("s_waitcnt vmcnt(6)" ::: "memory");
  __builtin_amdgcn_s_barrier();
  asm volatile("" ::: "memory");

  for (int tt = 0; tt < NT; ++tt) {
    const int cur = tt % 3;
    if (tt + 2 < NT) stage((tt + 2) % 3, (tt + 2) * BK);
    f16x8 af[4];
#pragma unroll
    for (int m = 0; m < 4; ++m)
      af[m] = *((const f16x8*)(&As[cur][(wr * 64 + m * 16 + fr) * BK + koff]));
#pragma unroll
    for (int h = 0; h < 4; ++h) {
      f16x8 bf[2];
#pragma unroll
      for (int n = 0; n < 2; ++n)
        bf[n] = *((const f16x8*)(&Bs[cur][h][(wc * 32 + n * 16 + fr) * BK + koff]));
#pragma unroll
      for (int m = 0; m < 4; ++m)
#pragma unroll
        for (int n = 0; n < 2; ++n)
          acc[h][m][n] = __builtin_amdgcn_mfma_f32_16x16x32_f16(af[m], bf[n], acc[h][m][n], 0, 0, 0);
    }
    // tile tt+1 must be landed before next iteration reads it:
    // after staging tile tt+2, "all but newest 6" == tiles <= tt+1.
    if (tt + 2 < NT) asm volatile("s_waitcnt vmcnt(6)" ::: "memory");
    else             asm volatile("s_waitcnt vmcnt(0)" ::: "memory");
    __builtin_amdgcn_s_barrier();
    asm volatile("" ::: "memory");
  }

#pragma unroll
  for (int m = 0; m < 4; ++m) {
#pragma unroll
    for (int n = 0; n < 2; ++n) {
      const int colg = (int)brow0 + wc * 32 + n * 16 + (lane & 15);
      const float B1 = b1[colg], B2 = b2[colg], BA = ba[colg], BT = bt[colg];
#pragma unroll
      for (int i = 0; i < 4; ++i) {
        const int rowg = (int)arow0 + wr * 64 + m * 16 + (lane >> 4) * 4 + i;
        const float ff1 = tanhf(acc[0][m][n][i] + B1);
        const float ff2 = tanhf(acc[1][m][n][i] + B2);
        const float ta = acc[2][m][n][i] + BA;
        const float tb = acc[3][m][n][i] + BT;
        const float z = ta * ts[rowg] + tb;
        const float ti = 1.0f / (1.0f + __expf(-z));
        out[(size_t)rowg * N + colg] = ff1 + ti * (ff2 - ff1);
      }
    }
  }
}

// ---- launch -------------------------------------------------------------

extern "C" void kernel_launch(void* const* d_in, const int* in_sizes, int n_in,
                              void* d_out, int out_size, void* d_ws, size_t ws_size,
                              hipStream_t stream) {
  const float* input = (const float*)d_in[0];
  const float* hx    = (const float*)d_in[1];
  const float* ts    = (const float*)d_in[2];
  const float* Wb    = (const float*)d_in[3];
  const float* bb    = (const float*)d_in[4];
  const float* W1    = (const float*)d_in[5];
  const float* b1    = (const float*)d_in[6];
  const float* W2    = (const float*)d_in[7];
  const float* b2    = (const float*)d_in[8];
  const float* Wa    = (const float*)d_in[9];
  const float* ba    = (const float*)d_in[10];
  const float* Wt    = (const float*)d_in[11];
  const float* bt    = (const float*)d_in[12];
  float* out = (float*)d_out;

  char* ws = (char*)d_ws;
  f16* x_f16  = (f16*)ws;  ws += (size_t)B_ * CAT_ * 2;
  f16* h_f16  = (f16*)ws;  ws += (size_t)B_ * UNITS_ * 2;
  f16* Wb_f16 = (f16*)ws;  ws += (size_t)UNITS_ * CAT_ * 2;
  f16* Wh_f16 = (f16*)ws;  ws += (size_t)4 * HID_ * UNITS_ * 2;

  build_x_kernel<<<(B_ * (CAT_ / 4) + 255) / 256, 256, 0, stream>>>(input, hx, x_f16);
  cvt_all_kernel<<<dim3((UNITS_ * CAT_ / 4 + 255) / 256, 5), 256, 0, stream>>>(
      Wb, W1, W2, Wa, Wt, Wb_f16, Wh_f16);

  gemm1_kernel<<<dim3(128 * 8), 256, 0, stream>>>(x_f16, Wb_f16, bb, h_f16);
  gemm2_kernel<<<dim3(128 * 8), 256, 0, stream>>>(h_f16, Wh_f16, b1, b2, ba, bt, ts, out);
}

// Round 3
// 166.949 us; speedup vs baseline: 1.6222x; 1.0299x over previous
//
#include <hip/hip_runtime.h>

// CfC cell, fp16-MFMA implementation.
//   h   = 1.7159*tanh(0.666*(concat(input,hx) @ Wb^T + bb))   [B,1024]
//   ff1 = tanh(h@W1^T+b1), ff2 = tanh(h@W2^T+b2)
//   t   = sigmoid((h@Wa^T+ba)*ts + (h@Wt^T+bt))
//   out = ff1 + t*(ff2-ff1)                                   [B,512]
// Round 3: chunk-XOR LDS swizzle (T2, involution within 64B rows) applied
// via pre-swizzled global_load_lds source + XOR'd read chunk; both GEMMs on
// the 3-buffer counted-vmcnt pipeline (T3+T4); XCD swizzle (T1).

typedef _Float16 f16;
typedef _Float16 f16x8 __attribute__((ext_vector_type(8)));
typedef _Float16 f16x4 __attribute__((ext_vector_type(4)));
typedef float f32x4 __attribute__((ext_vector_type(4)));

static constexpr int B_ = 16384, IN_ = 256, HID_ = 512, UNITS_ = 1024, CAT_ = 768;

__device__ __forceinline__ void gload_lds16(const void* g, void* l) {
  __builtin_amdgcn_global_load_lds(
      (const __attribute__((address_space(1))) void*)g,
      (__attribute__((address_space(3))) void*)l, 16, 0, 0);
}

// ---- conversion kernels -------------------------------------------------

__global__ void build_x_kernel(const float* __restrict__ inp,
                               const float* __restrict__ hx,
                               f16* __restrict__ x) {
  const int per_row = CAT_ / 4;  // 192 float4-groups per row
  int gid = blockIdx.x * blockDim.x + threadIdx.x;
  if (gid >= B_ * per_row) return;
  int b = gid / per_row, j = gid - b * per_row;
  float4 v;
  if (j < IN_ / 4) v = ((const float4*)(inp + (size_t)b * IN_))[j];
  else             v = ((const float4*)(hx  + (size_t)b * HID_))[j - IN_ / 4];
  f16x4 o = {(f16)v.x, (f16)v.y, (f16)v.z, (f16)v.w};
  *((f16x4*)(x + (size_t)b * CAT_ + j * 4)) = o;
}

__global__ void cvt_all_kernel(const float* __restrict__ Wb,
                               const float* __restrict__ W1,
                               const float* __restrict__ W2,
                               const float* __restrict__ Wa,
                               const float* __restrict__ Wt,
                               f16* __restrict__ dWb, f16* __restrict__ dWh) {
  const int seg = blockIdx.y;
  const int i = blockIdx.x * blockDim.x + threadIdx.x;
  const float* s;
  f16* d;
  int n4;
  if (seg == 0) {
    s = Wb; d = dWb; n4 = UNITS_ * CAT_ / 4;
  } else {
    const float* srcs[4] = {W1, W2, Wa, Wt};
    s = srcs[seg - 1];
    d = dWh + (size_t)(seg - 1) * HID_ * UNITS_;
    n4 = HID_ * UNITS_ / 4;
  }
  if (i >= n4) return;
  float4 v = ((const float4*)s)[i];
  f16x4 o = {(f16)v.x, (f16)v.y, (f16)v.z, (f16)v.w};
  ((f16x4*)d)[i] = o;
}

// LDS swizzle: rows are 64B = 4 chunks of 16B. Logical chunk c of row r is
// stored at physical chunk c ^ ((r>>1)&3) (involution, bits 4-5 only).
// Staging lane t (writes LDS linear byte t*16 = row t>>2, phys chunk t&3)
// therefore fetches global chunk (t&3)^((t>>3)&3). Readers of row R chunk
// c=lane>>4 read phys chunk (lane>>4)^((R>>1)&3); since R = base16k + fr
// with fr=lane&15, (R>>1)&3 == (lane>>1)&3 — a per-lane constant.

// ---- GEMM1: h = lecun_tanh(X @ Wb^T + bb) ------------------------------
// 128x128 tile, BK=32, 4 waves (2x2). 3-buffer counted-vmcnt pipeline.

__global__ __launch_bounds__(256) void gemm1_kernel(
    const f16* __restrict__ X, const f16* __restrict__ Wb,
    const float* __restrict__ bb, f16* __restrict__ H) {
  constexpr int BM = 128, BN = 128, BK = 32, K = CAT_, N = UNITS_;
  constexpr int NT = K / BK;  // 24
  __shared__ f16 As[3][BM * BK];   // 24 KB
  __shared__ f16 Bs[3][BN * BK];   // 24 KB
  const int t = threadIdx.x;
  const int lane = t & 63, wid = t >> 6;
  const int wr = wid >> 1, wc = wid & 1;
  const int wg = (blockIdx.x & 7) * 128 + (blockIdx.x >> 3);  // XCD swizzle
  const int bc = wg & 7;    // N/BN = 8
  const int br = wg >> 3;
  const size_t arow0 = (size_t)br * BM;
  const size_t brow0 = (size_t)bc * BN;

  f32x4 acc[4][4] = {};

  const int srow = t >> 2;
  const int schunk = ((t & 3) ^ ((t >> 3) & 3)) * 8;  // pre-swizzled source
  const f16* aptr0 = X + (arow0 + srow) * K + schunk;
  const f16* aptr1 = X + (arow0 + 64 + srow) * K + schunk;
  const f16* bptr0 = Wb + (brow0 + srow) * K + schunk;
  const f16* bptr1 = Wb + (brow0 + 64 + srow) * K + schunk;
  const int l8 = t * 8;
  const int fr = lane & 15;
  const int ksw = ((lane >> 4) ^ ((lane >> 1) & 3)) * 8;  // swizzled read chunk

  auto stage = [&](int buf, int k0) {
    gload_lds16(aptr0 + k0, &As[buf][l8]);
    gload_lds16(aptr1 + k0, &As[buf][64 * BK + l8]);
    gload_lds16(bptr0 + k0, &Bs[buf][l8]);
    gload_lds16(bptr1 + k0, &Bs[buf][64 * BK + l8]);
  };

  stage(0, 0);
  stage(1, BK);
  asm volatile("s_waitcnt vmcnt(4)" ::: "memory");  // tile 0 landed
  __builtin_amdgcn_s_barrier();
  asm volatile("" ::: "memory");

  for (int tt = 0; tt < NT; ++tt) {
    const int cur = tt % 3;
    if (tt + 2 < NT) stage((tt + 2) % 3, (tt + 2) * BK);
    f16x8 af[4], bf[4];
#pragma unroll
    for (int m = 0; m < 4; ++m)
      af[m] = *((const f16x8*)(&As[cur][(wr * 64 + m * 16 + fr) * BK + ksw]));
#pragma unroll
    for (int n = 0; n < 4; ++n)
      bf[n] = *((const f16x8*)(&Bs[cur][(wc * 64 + n * 16 + fr) * BK + ksw]));
#pragma unroll
    for (int m = 0; m < 4; ++m)
#pragma unroll
      for (int n = 0; n < 4; ++n)
        acc[m][n] = __builtin_amdgcn_mfma_f32_16x16x32_f16(af[m], bf[n], acc[m][n], 0, 0, 0);
    if (tt + 2 < NT) asm volatile("s_waitcnt vmcnt(4)" ::: "memory");
    else             asm volatile("s_waitcnt vmcnt(0)" ::: "memory");
    __builtin_amdgcn_s_barrier();
    asm volatile("" ::: "memory");
  }

#pragma unroll
  for (int m = 0; m < 4; ++m) {
#pragma unroll
    for (int n = 0; n < 4; ++n) {
      const int colg = (int)brow0 + wc * 64 + n * 16 + (lane & 15);
      const float bias = bb[colg];
#pragma unroll
      for (int i = 0; i < 4; ++i) {
        const int rowg = (int)arow0 + wr * 64 + m * 16 + (lane >> 4) * 4 + i;
        float v = acc[m][n][i] + bias;
        v = 1.7159f * tanhf(0.666f * v);
        H[(size_t)rowg * N + colg] = (f16)v;
      }
    }
  }
}

// ---- GEMM2: four heads fused, 3-buffer counted-vmcnt pipeline -----------
// 128x64-per-head tile, BK=32, 4 waves (2x2).

__global__ __launch_bounds__(256) void gemm2_kernel(
    const f16* __restrict__ H, const f16* __restrict__ W,
    const float* __restrict__ b1, const float* __restrict__ b2,
    const float* __restrict__ ba, const float* __restrict__ bt,
    const float* __restrict__ ts, float* __restrict__ out) {
  constexpr int BM = 128, BN = 64, BK = 32, K = UNITS_, N = HID_;
  constexpr int NT = K / BK;  // 32
  __shared__ f16 As[3][BM * BK];      // 24 KB
  __shared__ f16 Bs[3][4][BN * BK];   // 48 KB
  const int t = threadIdx.x;
  const int lane = t & 63, wid = t >> 6;
  const int wr = wid >> 1, wc = wid & 1;
  const int wg = (blockIdx.x & 7) * 128 + (blockIdx.x >> 3);
  const int bc = wg & 7;    // N/BN = 8
  const int br = wg >> 3;
  const size_t arow0 = (size_t)br * BM;
  const size_t brow0 = (size_t)bc * BN;

  f32x4 acc[4][4][2] = {};  // [head][m][n]

  const int srow = t >> 2;
  const int schunk = ((t & 3) ^ ((t >> 3) & 3)) * 8;
  const f16* aptr0 = H + (arow0 + srow) * K + schunk;
  const f16* aptr1 = H + (arow0 + 64 + srow) * K + schunk;
  const f16* bptrs[4];
#pragma unroll
  for (int h = 0; h < 4; ++h)
    bptrs[h] = W + ((size_t)h * N + brow0 + srow) * K + schunk;
  const int l8 = t * 8;
  const int fr = lane & 15;
  const int ksw = ((lane >> 4) ^ ((lane >> 1) & 3)) * 8;

  auto stage = [&](int buf, int k0) {
    gload_lds16(aptr0 + k0, &As[buf][l8]);
    gload_lds16(aptr1 + k0, &As[buf][64 * BK + l8]);
#pragma unroll
    for (int h = 0; h < 4; ++h)
      gload_lds16(bptrs[h] + k0, &Bs[buf][h][l8]);
  };

  stage(0, 0);
  stage(1, BK);
  asm volatile("s_waitcnt vmcnt(6)" ::: "memory");  // tile 0 landed
  __builtin_amdgcn_s_barrier();
  asm volatile("" ::: "memory");

  for (int tt = 0; tt < NT; ++tt) {
    const int cur = tt % 3;
    if (tt + 2 < NT) stage((tt + 2) % 3, (tt + 2) * BK);
    f16x8 af[4];
#pragma unroll
    for (int m = 0; m < 4; ++m)
      af[m] = *((const f16x8*)(&As[cur][(wr * 64 + m * 16 + fr) * BK + ksw]));
#pragma unroll
    for (int h = 0; h < 4; ++h) {
      f16x8 bf[2];
#pragma unroll
      for (int n = 0; n < 2; ++n)
        bf[n] = *((const f16x8*)(&Bs[cur][h][(wc * 32 + n * 16 + fr) * BK + ksw]));
#pragma unroll
      for (int m = 0; m < 4; ++m)
#pragma unroll
        for (int n = 0; n < 2; ++n)
          acc[h][m][n] = __builtin_amdgcn_mfma_f32_16x16x32_f16(af[m], bf[n], acc[h][m][n], 0, 0, 0);
    }
    if (tt + 2 < NT) asm volatile("s_waitcnt vmcnt(6)" ::: "memory");
    else             asm volatile("s_waitcnt vmcnt(0)" ::: "memory");
    __builtin_amdgcn_s_barrier();
    asm volatile("" ::: "memory");
  }

#pragma unroll
  for (int m = 0; m < 4; ++m) {
#pragma unroll
    for (int n = 0; n < 2; ++n) {
      const int colg = (int)brow0 + wc * 32 + n * 16 + (lane & 15);
      const float B1 = b1[colg], B2 = b2[colg], BA = ba[colg], BT = bt[colg];
#pragma unroll
      for (int i = 0; i < 4; ++i) {
        const int rowg = (int)arow0 + wr * 64 + m * 16 + (lane >> 4) * 4 + i;
        const float ff1 = tanhf(acc[0][m][n][i] + B1);
        const float ff2 = tanhf(acc[1][m][n][i] + B2);
        const float ta = acc[2][m][n][i] + BA;
        const float tb = acc[3][m][n][i] + BT;
        const float z = ta * ts[rowg] + tb;
        const float ti = 1.0f / (1.0f + __expf(-z));
        out[(size_t)rowg * N + colg] = ff1 + ti * (ff2 - ff1);
      }
    }
  }
}

// ---- launch -------------------------------------------------------------

extern "C" void kernel_launch(void* const* d_in, const int* in_sizes, int n_in,
                              void* d_out, int out_size, void* d_ws, size_t ws_size,
                              hipStream_t stream) {
  const float* input = (const float*)d_in[0];
  const float* hx    = (const float*)d_in[1];
  const float* ts    = (const float*)d_in[2];
  const float* Wb    = (const float*)d_in[3];
  const float* bb    = (const float*)d_in[4];
  const float* W1    = (const float*)d_in[5];
  const float* b1    = (const float*)d_in[6];
  const float* W2    = (const float*)d_in[7];
  const float* b2    = (const float*)d_in[8];
  const float* Wa    = (const float*)d_in[9];
  const float* ba    = (const float*)d_in[10];
  const float* Wt    = (const float*)d_in[11];
  const float* bt    = (const float*)d_in[12];
  float* out = (float*)d_out;

  char* ws = (char*)d_ws;
  f16* x_f16  = (f16*)ws;  ws += (size_t)B_ * CAT_ * 2;
  f16* h_f16  = (f16*)ws;  ws += (size_t)B_ * UNITS_ * 2;
  f16* Wb_f16 = (f16*)ws;  ws += (size_t)UNITS_ * CAT_ * 2;
  f16* Wh_f16 = (f16*)ws;  ws += (size_t)4 * HID_ * UNITS_ * 2;

  build_x_kernel<<<(B_ * (CAT_ / 4) + 255) / 256, 256, 0, stream>>>(input, hx, x_f16);
  cvt_all_kernel<<<dim3((UNITS_ * CAT_ / 4 + 255) / 256, 5), 256, 0, stream>>>(
      Wb, W1, W2, Wa, Wt, Wb_f16, Wh_f16);

  gemm1_kernel<<<dim3(128 * 8), 256, 0, stream>>>(x_f16, Wb_f16, bb, h_f16);
  gemm2_kernel<<<dim3(128 * 8), 256, 0, stream>>>(h_f16, Wh_f16, b1, b2, ba, bt, ts, out);
}

// Round 4
// 159.474 us; speedup vs baseline: 1.6983x; 1.0469x over previous
//
#include <hip/hip_runtime.h>

// CfC cell, fp16-MFMA implementation.
//   h   = 1.7159*tanh(0.666*(concat(input,hx) @ Wb^T + bb))   [B,1024]
//   ff1 = tanh(h@W1^T+b1), ff2 = tanh(h@W2^T+b2)
//   t   = sigmoid((h@Wa^T+ba)*ts + (h@Wt^T+bt))
//   out = ff1 + t*(ff2-ff1)                                   [B,512]
// Round 4: gemm2 ported to the m201 8-phase-style template: 512 thr / 8
// waves, 256x(4x64) tile, BK=64, 2x64KB LDS dbuf, 4 phases per K-tile with
// {ds_read || global_load_lds || MFMA} interleave, counted vmcnt(2) (T3+T4),
// setprio around MFMA clusters (T5), 3-bit chunk-XOR swizzle (T2, rule-21
// both-sides involution). gemm1 kept as round-3 pipeline.

typedef _Float16 f16;
typedef _Float16 f16x8 __attribute__((ext_vector_type(8)));
typedef _Float16 f16x4 __attribute__((ext_vector_type(4)));
typedef float f32x4 __attribute__((ext_vector_type(4)));

static constexpr int B_ = 16384, IN_ = 256, HID_ = 512, UNITS_ = 1024, CAT_ = 768;

__device__ __forceinline__ void gload_lds16(const void* g, void* l) {
  __builtin_amdgcn_global_load_lds(
      (const __attribute__((address_space(1))) void*)g,
      (__attribute__((address_space(3))) void*)l, 16, 0, 0);
}

// ---- conversion kernels -------------------------------------------------

__global__ void build_x_kernel(const float* __restrict__ inp,
                               const float* __restrict__ hx,
                               f16* __restrict__ x) {
  const int per_row = CAT_ / 4;
  int gid = blockIdx.x * blockDim.x + threadIdx.x;
  if (gid >= B_ * per_row) return;
  int b = gid / per_row, j = gid - b * per_row;
  float4 v;
  if (j < IN_ / 4) v = ((const float4*)(inp + (size_t)b * IN_))[j];
  else             v = ((const float4*)(hx  + (size_t)b * HID_))[j - IN_ / 4];
  f16x4 o = {(f16)v.x, (f16)v.y, (f16)v.z, (f16)v.w};
  *((f16x4*)(x + (size_t)b * CAT_ + j * 4)) = o;
}

__global__ void cvt_all_kernel(const float* __restrict__ Wb,
                               const float* __restrict__ W1,
                               const float* __restrict__ W2,
                               const float* __restrict__ Wa,
                               const float* __restrict__ Wt,
                               f16* __restrict__ dWb, f16* __restrict__ dWh) {
  const int seg = blockIdx.y;
  const int i = blockIdx.x * blockDim.x + threadIdx.x;
  const float* s;
  f16* d;
  int n4;
  if (seg == 0) {
    s = Wb; d = dWb; n4 = UNITS_ * CAT_ / 4;
  } else {
    const float* srcs[4] = {W1, W2, Wa, Wt};
    s = srcs[seg - 1];
    d = dWh + (size_t)(seg - 1) * HID_ * UNITS_;
    n4 = HID_ * UNITS_ / 4;
  }
  if (i >= n4) return;
  float4 v = ((const float4*)s)[i];
  f16x4 o = {(f16)v.x, (f16)v.y, (f16)v.z, (f16)v.w};
  ((f16x4*)d)[i] = o;
}

// ---- GEMM1: h = lecun_tanh(X @ Wb^T + bb) ------------------------------
// Round-3 structure (3-buffer counted-vmcnt, 64B-row chunk swizzle). Kept.

__global__ __launch_bounds__(256) void gemm1_kernel(
    const f16* __restrict__ X, const f16* __restrict__ Wb,
    const float* __restrict__ bb, f16* __restrict__ H) {
  constexpr int BM = 128, BN = 128, BK = 32, K = CAT_, N = UNITS_;
  constexpr int NT = K / BK;  // 24
  __shared__ f16 As[3][BM * BK];
  __shared__ f16 Bs[3][BN * BK];
  const int t = threadIdx.x;
  const int lane = t & 63, wid = t >> 6;
  const int wr = wid >> 1, wc = wid & 1;
  const int wg = (blockIdx.x & 7) * 128 + (blockIdx.x >> 3);
  const int bc = wg & 7;
  const int br = wg >> 3;
  const size_t arow0 = (size_t)br * BM;
  const size_t brow0 = (size_t)bc * BN;

  f32x4 acc[4][4] = {};

  const int srow = t >> 2;
  const int schunk = ((t & 3) ^ ((t >> 3) & 3)) * 8;
  const f16* aptr0 = X + (arow0 + srow) * K + schunk;
  const f16* aptr1 = X + (arow0 + 64 + srow) * K + schunk;
  const f16* bptr0 = Wb + (brow0 + srow) * K + schunk;
  const f16* bptr1 = Wb + (brow0 + 64 + srow) * K + schunk;
  const int l8 = t * 8;
  const int fr = lane & 15;
  const int ksw = ((lane >> 4) ^ ((lane >> 1) & 3)) * 8;

  auto stage = [&](int buf, int k0) {
    gload_lds16(aptr0 + k0, &As[buf][l8]);
    gload_lds16(aptr1 + k0, &As[buf][64 * BK + l8]);
    gload_lds16(bptr0 + k0, &Bs[buf][l8]);
    gload_lds16(bptr1 + k0, &Bs[buf][64 * BK + l8]);
  };

  stage(0, 0);
  stage(1, BK);
  asm volatile("s_waitcnt vmcnt(4)" ::: "memory");
  __builtin_amdgcn_s_barrier();
  asm volatile("" ::: "memory");

  for (int tt = 0; tt < NT; ++tt) {
    const int cur = tt % 3;
    if (tt + 2 < NT) stage((tt + 2) % 3, (tt + 2) * BK);
    f16x8 af[4], bf[4];
#pragma unroll
    for (int m = 0; m < 4; ++m)
      af[m] = *((const f16x8*)(&As[cur][(wr * 64 + m * 16 + fr) * BK + ksw]));
#pragma unroll
    for (int n = 0; n < 4; ++n)
      bf[n] = *((const f16x8*)(&Bs[cur][(wc * 64 + n * 16 + fr) * BK + ksw]));
#pragma unroll
    for (int m = 0; m < 4; ++m)
#pragma unroll
      for (int n = 0; n < 4; ++n)
        acc[m][n] = __builtin_amdgcn_mfma_f32_16x16x32_f16(af[m], bf[n], acc[m][n], 0, 0, 0);
    if (tt + 2 < NT) asm volatile("s_waitcnt vmcnt(4)" ::: "memory");
    else             asm volatile("s_waitcnt vmcnt(0)" ::: "memory");
    __builtin_amdgcn_s_barrier();
    asm volatile("" ::: "memory");
  }

#pragma unroll
  for (int m = 0; m < 4; ++m) {
#pragma unroll
    for (int n = 0; n < 4; ++n) {
      const int colg = (int)brow0 + wc * 64 + n * 16 + (lane & 15);
      const float bias = bb[colg];
#pragma unroll
      for (int i = 0; i < 4; ++i) {
        const int rowg = (int)arow0 + wr * 64 + m * 16 + (lane >> 4) * 4 + i;
        float v = acc[m][n][i] + bias;
        v = 1.7159f * tanhf(0.666f * v);
        H[(size_t)rowg * N + colg] = (f16)v;
      }
    }
  }
}

// ---- GEMM2: four heads fused, 8-phase-style template --------------------
// Block: 512 thr, 8 waves (wr in {0,1} x wc in {0..3}). Tile: 256 rows x
// (4 heads x 64 cols). BK=64. LDS: A,B each 2x[256][64] f16 = 128 KB.
// Wave tile: 128 rows x 16 cols x 4 heads. acc[8][4] f32x4 = 128 VGPR.
// Per K-tile: 4 phases, each {ds_read subtile; 2 gload_lds; bar; prio1;
// 16 MFMA; prio0; [vmcnt(2)]; bar}. Staging order per tile: A p0,p1 | A
// p2,p3 | B p0,p1 | B p2,p3 (pass p covers LDS rows p*64..p*64+63; B pass
// p == head p). Waits: end-P4 vmcnt(2) -> loads 1-6 done (next P1 needs);
// end-P1 vmcnt(2) -> prev loads 7,8 done (P2 needs).

__global__ __launch_bounds__(512, 2) void gemm2_kernel(
    const f16* __restrict__ H, const f16* __restrict__ W,
    const float* __restrict__ b1, const float* __restrict__ b2,
    const float* __restrict__ ba, const float* __restrict__ bt,
    const float* __restrict__ ts, float* __restrict__ out) {
  constexpr int BK = 64, K = UNITS_;
  constexpr int NT = K / BK;  // 16
  __shared__ f16 As[2][256 * BK];  // 64 KB
  __shared__ f16 Bs[2][256 * BK];  // 64 KB
  const int t = threadIdx.x;
  const int lane = t & 63, wid = t >> 6;
  const int wr = wid >> 2;      // 0..1 : row half (128 rows)
  const int wc = wid & 3;       // 0..3 : 16-col group
  // XCD swizzle: 512 blocks, 8 XCDs, 64 contiguous per XCD (bijective)
  const int wg = (blockIdx.x & 7) * 64 + (blockIdx.x >> 3);
  const int bc = wg & 7;        // 8 col-blocks (64 cols each)
  const int br = wg >> 3;       // 64 row-blocks
  const int arow0 = br * 256;
  const int bcol0 = bc * 64;

  f32x4 acc[8][4] = {};  // [m over 128 rows][head]

  // staging: thread t handles chunk-rows trow + p*64, phys chunk t&7
  const int trow = t >> 3;                          // 0..63
  const int schunk = ((t & 7) ^ (trow & 7)) * 8;    // pre-swizzled source (f16)
  const f16* aP[4];
  const f16* bP[4];
#pragma unroll
  for (int p = 0; p < 4; ++p) {
    aP[p] = H + (size_t)(arow0 + trow + p * 64) * K + schunk;
    bP[p] = W + (size_t)(p * 512 + bcol0 + trow) * K + schunk;  // head p
  }

  const int fr = lane & 15;
  const int klo = lane >> 4;                        // 0..3
  const int kx0 = ((0 * 4 + klo) ^ (fr & 7)) * 8;   // kk=0 read chunk (f16)
  const int kx1 = ((1 * 4 + klo) ^ (fr & 7)) * 8;   // kk=1

#define STAGE_A(nb, p, k0) gload_lds16(aP[p] + (k0), &As[nb][(t + (p)*512) * 8])
#define STAGE_B(nb, p, k0) gload_lds16(bP[p] + (k0), &Bs[nb][(t + (p)*512) * 8])
#define BARRIER() do { asm volatile("" ::: "memory"); __builtin_amdgcn_s_barrier(); asm volatile("" ::: "memory"); } while (0)

  // prologue: full tile 0
#pragma unroll
  for (int p = 0; p < 4; ++p) STAGE_A(0, p, 0);
#pragma unroll
  for (int p = 0; p < 4; ++p) STAGE_B(0, p, 0);
  asm volatile("s_waitcnt vmcnt(0)" ::: "memory");
  __builtin_amdgcn_s_barrier();
  asm volatile("" ::: "memory");

  f16x8 aF[4][2], bF0[2][2], bF1[2][2];

  for (int tt = 0; tt < NT; ++tt) {
    const int cur = tt & 1, nxt = cur ^ 1;
    const int k1 = (tt + 1) * BK;
    const bool more = (tt + 1 < NT);

    // ---- P1: read A[mh0] + B[nh0]; stage A p0,p1 ----
#pragma unroll
    for (int m4 = 0; m4 < 4; ++m4) {
      const int r = (wr * 128 + m4 * 16 + fr) * BK;
      aF[m4][0] = *((const f16x8*)(&As[cur][r + kx0]));
      aF[m4][1] = *((const f16x8*)(&As[cur][r + kx1]));
    }
#pragma unroll
    for (int n2 = 0; n2 < 2; ++n2) {
      const int r = (n2 * 64 + wc * 16 + fr) * BK;
      bF0[n2][0] = *((const f16x8*)(&Bs[cur][r + kx0]));
      bF0[n2][1] = *((const f16x8*)(&Bs[cur][r + kx1]));
    }
    if (more) { STAGE_A(nxt, 0, k1); STAGE_A(nxt, 1, k1); }
    BARRIER();
    __builtin_amdgcn_s_setprio(1);
#pragma unroll
    for (int m4 = 0; m4 < 4; ++m4)
#pragma unroll
      for (int n2 = 0; n2 < 2; ++n2)
#pragma unroll
        for (int kk = 0; kk < 2; ++kk)
          acc[m4][n2] = __builtin_amdgcn_mfma_f32_16x16x32_f16(aF[m4][kk], bF0[n2][kk], acc[m4][n2], 0, 0, 0);
    __builtin_amdgcn_s_setprio(0);
    if (more) asm volatile("s_waitcnt vmcnt(2)" ::: "memory");
    else      asm volatile("s_waitcnt vmcnt(0)" ::: "memory");
    BARRIER();

    // ---- P2: read B[nh1]; stage A p2,p3 ----
#pragma unroll
    for (int n2 = 0; n2 < 2; ++n2) {
      const int r = ((2 + n2) * 64 + wc * 16 + fr) * BK;
      bF1[n2][0] = *((const f16x8*)(&Bs[cur][r + kx0]));
      bF1[n2][1] = *((const f16x8*)(&Bs[cur][r + kx1]));
    }
    if (more) { STAGE_A(nxt, 2, k1); STAGE_A(nxt, 3, k1); }
    BARRIER();
    __builtin_amdgcn_s_setprio(1);
#pragma unroll
    for (int m4 = 0; m4 < 4; ++m4)
#pragma unroll
      for (int n2 = 0; n2 < 2; ++n2)
#pragma unroll
        for (int kk = 0; kk < 2; ++kk)
          acc[m4][2 + n2] = __builtin_amdgcn_mfma_f32_16x16x32_f16(aF[m4][kk], bF1[n2][kk], acc[m4][2 + n2], 0, 0, 0);
    __builtin_amdgcn_s_setprio(0);
    BARRIER();

    // ---- P3: read A[mh1]; stage B p0,p1 ----
#pragma unroll
    for (int m4 = 0; m4 < 4; ++m4) {
      const int r = (wr * 128 + 64 + m4 * 16 + fr) * BK;
      aF[m4][0] = *((const f16x8*)(&As[cur][r + kx0]));
      aF[m4][1] = *((const f16x8*)(&As[cur][r + kx1]));
    }
    if (more) { STAGE_B(nxt, 0, k1); STAGE_B(nxt, 1, k1); }
    BARRIER();
    __builtin_amdgcn_s_setprio(1);
#pragma unroll
    for (int m4 = 0; m4 < 4; ++m4)
#pragma unroll
      for (int n2 = 0; n2 < 2; ++n2)
#pragma unroll
        for (int kk = 0; kk < 2; ++kk)
          acc[4 + m4][2 + n2] = __builtin_amdgcn_mfma_f32_16x16x32_f16(aF[m4][kk], bF1[n2][kk], acc[4 + m4][2 + n2], 0, 0, 0);
    __builtin_amdgcn_s_setprio(0);
    BARRIER();

    // ---- P4: (regs live); stage B p2,p3 ----
    if (more) { STAGE_B(nxt, 2, k1); STAGE_B(nxt, 3, k1); }
    BARRIER();
    __builtin_amdgcn_s_setprio(1);
#pragma unroll
    for (int m4 = 0; m4 < 4; ++m4)
#pragma unroll
      for (int n2 = 0; n2 < 2; ++n2)
#pragma unroll
        for (int kk = 0; kk < 2; ++kk)
          acc[4 + m4][n2] = __builtin_amdgcn_mfma_f32_16x16x32_f16(aF[m4][kk], bF0[n2][kk], acc[4 + m4][n2], 0, 0, 0);
    __builtin_amdgcn_s_setprio(0);
    if (more) asm volatile("s_waitcnt vmcnt(2)" ::: "memory");
    BARRIER();
  }
#undef STAGE_A
#undef STAGE_B
#undef BARRIER

  // epilogue: wave covers 128 rows x 16 cols x 4 heads; col fixed per lane
  const int colg = bcol0 + wc * 16 + fr;
  const float B1 = b1[colg], B2 = b2[colg], BA = ba[colg], BT = bt[colg];
#pragma unroll
  for (int m = 0; m < 8; ++m) {
#pragma unroll
    for (int i = 0; i < 4; ++i) {
      const int rowg = arow0 + wr * 128 + m * 16 + klo * 4 + i;
      const float ff1 = tanhf(acc[m][0][i] + B1);
      const float ff2 = tanhf(acc[m][1][i] + B2);
      const float ta = acc[m][2][i] + BA;
      const float tb = acc[m][3][i] + BT;
      const float z = ta * ts[rowg] + tb;
      const float ti = 1.0f / (1.0f + __expf(-z));
      out[(size_t)rowg * HID_ + colg] = ff1 + ti * (ff2 - ff1);
    }
  }
}

// ---- launch -------------------------------------------------------------

extern "C" void kernel_launch(void* const* d_in, const int* in_sizes, int n_in,
                              void* d_out, int out_size, void* d_ws, size_t ws_size,
                              hipStream_t stream) {
  const float* input = (const float*)d_in[0];
  const float* hx    = (const float*)d_in[1];
  const float* ts    = (const float*)d_in[2];
  const float* Wb    = (const float*)d_in[3];
  const float* bb    = (const float*)d_in[4];
  const float* W1    = (const float*)d_in[5];
  const float* b1    = (const float*)d_in[6];
  const float* W2    = (const float*)d_in[7];
  const float* b2    = (const float*)d_in[8];
  const float* Wa    = (const float*)d_in[9];
  const float* ba    = (const float*)d_in[10];
  const float* Wt    = (const float*)d_in[11];
  const float* bt    = (const float*)d_in[12];
  float* out = (float*)d_out;

  char* ws = (char*)d_ws;
  f16* x_f16  = (f16*)ws;  ws += (size_t)B_ * CAT_ * 2;
  f16* h_f16  = (f16*)ws;  ws += (size_t)B_ * UNITS_ * 2;
  f16* Wb_f16 = (f16*)ws;  ws += (size_t)UNITS_ * CAT_ * 2;
  f16* Wh_f16 = (f16*)ws;  ws += (size_t)4 * HID_ * UNITS_ * 2;

  build_x_kernel<<<(B_ * (CAT_ / 4) + 255) / 256, 256, 0, stream>>>(input, hx, x_f16);
  cvt_all_kernel<<<dim3((UNITS_ * CAT_ / 4 + 255) / 256, 5), 256, 0, stream>>>(
      Wb, W1, W2, Wa, Wt, Wb_f16, Wh_f16);

  gemm1_kernel<<<dim3(128 * 8), 256, 0, stream>>>(x_f16, Wb_f16, bb, h_f16);
  gemm2_kernel<<<dim3(64 * 8), 512, 0, stream>>>(h_f16, Wh_f16, b1, b2, ba, bt, ts, out);
}